// Round 8
// baseline (266.050 us; speedup 1.0000x reference)
//
#include <hip/hip_runtime.h>
#include <math.h>

typedef __attribute__((ext_vector_type(8))) short bf16x8;
typedef __attribute__((ext_vector_type(4))) float f32x4;
typedef __attribute__((ext_vector_type(16))) float f32x16;

__device__ __forceinline__ ushort f2bf(float f) {
  union { float f; unsigned u; } v; v.f = f;
  return (ushort)((v.u + 0x8000u) >> 16);
}

// async global->LDS, 16B per lane. lds base wave-uniform; lane i lands at base + i*16B.
__device__ __forceinline__ void g2l16(const void* g, void* l) {
  __builtin_amdgcn_global_load_lds((const __attribute__((address_space(1))) unsigned*)g,
                                   (__attribute__((address_space(3))) unsigned*)l, 16, 0, 0);
}

// ---------------- merged cast + zero kernel ----------------
// idx [0,1M): x -> xbf.  [1M,2M): weights -> wcat (Wq scaled).  [2M,3M): zero O32.
__global__ __launch_bounds__(256) void cast_all(const float* __restrict__ x,
                                                const float* __restrict__ Wq,
                                                const float* __restrict__ Wk,
                                                const float* __restrict__ Wv,
                                                const float* __restrict__ Wo,
                                                ushort* __restrict__ xbf,
                                                ushort* __restrict__ wcat,
                                                float4* __restrict__ O32) {
  int i = blockIdx.x * 256 + threadIdx.x;
  if (i < 1048576) {
    float4 v = ((const float4*)x)[i];
    ushort4 u; u.x = f2bf(v.x); u.y = f2bf(v.y); u.z = f2bf(v.z); u.w = f2bf(v.w);
    ((ushort4*)xbf)[i] = u;
  } else if (i < 2097152) {
    int j = i - 1048576;
    int sel = j >> 18;
    const float* src = (sel == 0) ? Wq : (sel == 1) ? Wk : (sel == 2) ? Wv : Wo;
    float scale = (sel == 0) ? 0.125f * 1.44269504088896f : 1.0f;  // fold D^-0.5 * log2e
    float4 v = ((const float4*)src)[j & 0x3FFFF];
    ushort4 u;
    u.x = f2bf(v.x * scale); u.y = f2bf(v.y * scale);
    u.z = f2bf(v.z * scale); u.w = f2bf(v.w * scale);
    ((ushort4*)wcat)[j] = u;
  } else {
    O32[i - 2097152] = float4{0.f, 0.f, 0.f, 0.f};
  }
}

// ---------------- QKV GEMM: C = A @ B^T, 128x128, BK=32, dbuf ----------------
// Q/K planes token-major; V blocks write Vt[bh][d][t] via LDS transpose in the epilogue.
__global__ __launch_bounds__(256) void gemm_qkv(const ushort* __restrict__ A,
                                                const ushort* __restrict__ B,
                                                ushort* __restrict__ C3,
                                                ushort* __restrict__ Vt) {
  const int K = 1024;
  __shared__ __align__(16) ushort smem[17408];   // staging 32KB / transpose T[128][136]
  ushort* As = smem;           // [2][128*32]
  ushort* Bs = smem + 8192;    // [2][128*32]
  const int m0 = blockIdx.y * 128, n0 = blockIdx.x * 128;
  const int tid = threadIdx.x, lane = tid & 63, wid = tid >> 6;
  const int quad = lane >> 4, lc = lane & 15;
  const int lrow = lane >> 2, lcol = (lane & 3) * 8;
  const int wm = (wid >> 1) * 64, wn = (wid & 1) * 64;

  f32x4 acc[4][4] = {};

  auto stage = [&](int k0, int nb) {
    const ushort* Ag = A + (size_t)(m0 + wid * 32 + lrow) * K + k0 + lcol;
    g2l16(Ag, &As[nb * 4096 + wid * 1024]);
    g2l16(Ag + (size_t)16 * K, &As[nb * 4096 + wid * 1024 + 512]);
    const ushort* Bg = B + (size_t)(n0 + wid * 32 + lrow) * K + k0 + lcol;
    g2l16(Bg, &Bs[nb * 4096 + wid * 1024]);
    g2l16(Bg + (size_t)16 * K, &Bs[nb * 4096 + wid * 1024 + 512]);
  };

  stage(0, 0);
  for (int k0 = 0; k0 < K; k0 += 32) {
    const int nb = (k0 >> 5) & 1;
    __syncthreads();
    if (k0 + 32 < K) stage(k0 + 32, nb ^ 1);

    bf16x8 af[4], bfr[4];
#pragma unroll
    for (int t = 0; t < 4; t++)
      af[t] = *(const bf16x8*)&As[nb * 4096 + (wm + t * 16 + lc) * 32 + quad * 8];
#pragma unroll
    for (int t = 0; t < 4; t++)
      bfr[t] = *(const bf16x8*)&Bs[nb * 4096 + (wn + t * 16 + lc) * 32 + quad * 8];
#pragma unroll
    for (int mt = 0; mt < 4; mt++)
#pragma unroll
      for (int nt = 0; nt < 4; nt++)
        acc[mt][nt] = __builtin_amdgcn_mfma_f32_16x16x32_bf16(af[mt], bfr[nt], acc[mt][nt], 0, 0, 0);
  }

  const int sel = n0 >> 10;   // 0=Q, 1=K, 2=V (block-uniform)
  if (sel < 2) {
#pragma unroll
    for (int mt = 0; mt < 4; mt++) {
#pragma unroll
      for (int r = 0; r < 4; r++) {
        int row = m0 + wm + mt * 16 + quad * 4 + r;
#pragma unroll
        for (int nt = 0; nt < 4; nt++) {
          int col = n0 + wn + nt * 16 + lc;
          size_t dst = ((size_t)sel << 22) + (size_t)row * 1024 + (col & 1023);
          C3[dst] = f2bf(acc[mt][nt][r]);
        }
      }
    }
  } else {
    // transpose through LDS: T[d_local 128][token_local 128], pitch 136
    __syncthreads();
#pragma unroll
    for (int mt = 0; mt < 4; mt++)
#pragma unroll
      for (int r = 0; r < 4; r++) {
        int tl = wm + mt * 16 + quad * 4 + r;
#pragma unroll
        for (int nt = 0; nt < 4; nt++)
          smem[(wn + nt * 16 + lc) * 136 + tl] = f2bf(acc[mt][nt][r]);
      }
    __syncthreads();
    const int hd0 = n0 - 2048, b = m0 >> 11, t_base = m0 & 2047;
#pragma unroll
    for (int i = 0; i < 8; i++) {
      int idx = i * 256 + tid;
      int dl = idx >> 4, tc = (idx & 15) * 8;
      uint4 v = *(const uint4*)&smem[dl * 136 + tc];
      int hd = hd0 + dl;
      *(uint4*)(Vt + (size_t)(b * 16 + (hd >> 6)) * 131072 +
                (size_t)(hd & 63) * 2048 + t_base + tc) = v;
    }
  }
}

// ---------------- proj GEMM: out[4096][1024] = attn_out @ Wo^T + bo, BK=64 ----------------
__global__ __launch_bounds__(256) void gemm_proj(const ushort* __restrict__ A,
                                                 const ushort* __restrict__ B,
                                                 float* __restrict__ C,
                                                 const float* __restrict__ bias) {
  const int K = 1024;
  __shared__ __align__(16) ushort As[2][2][128 * 32];
  __shared__ __align__(16) ushort Bs[2][2][64 * 32];
  const int m0 = blockIdx.y * 128, n0 = blockIdx.x * 64;
  const int tid = threadIdx.x, lane = tid & 63, wid = tid >> 6;
  const int quad = lane >> 4, lc = lane & 15;
  const int lrow = lane >> 2, lcol = (lane & 3) * 8;
  const int wm = (wid >> 1) * 64, wn = (wid & 1) * 32;

  f32x4 acc[4][2] = {};

  auto stage = [&](int k0, int nb) {
    const ushort* Ag = A + (size_t)(m0 + wid * 32 + lrow) * K + k0 + lcol;
    g2l16(Ag,                       &As[nb][0][wid * 1024]);
    g2l16(Ag + (size_t)16 * K,      &As[nb][0][wid * 1024 + 512]);
    g2l16(Ag + 32,                  &As[nb][1][wid * 1024]);
    g2l16(Ag + (size_t)16 * K + 32, &As[nb][1][wid * 1024 + 512]);
    const ushort* Bg = B + (size_t)(n0 + wid * 16 + lrow) * K + k0 + lcol;
    g2l16(Bg,      &Bs[nb][0][wid * 512]);
    g2l16(Bg + 32, &Bs[nb][1][wid * 512]);
  };

  stage(0, 0);
  for (int k0 = 0; k0 < K; k0 += 64) {
    const int nb = (k0 >> 6) & 1;
    __syncthreads();
    if (k0 + 64 < K) stage(k0 + 64, nb ^ 1);

#pragma unroll
    for (int ks = 0; ks < 2; ks++) {
      bf16x8 af[4], bfr[2];
#pragma unroll
      for (int t = 0; t < 4; t++)
        af[t] = *(const bf16x8*)&As[nb][ks][(wm + t * 16 + lc) * 32 + quad * 8];
#pragma unroll
      for (int t = 0; t < 2; t++)
        bfr[t] = *(const bf16x8*)&Bs[nb][ks][(wn + t * 16 + lc) * 32 + quad * 8];
#pragma unroll
      for (int mt = 0; mt < 4; mt++)
#pragma unroll
        for (int nt = 0; nt < 2; nt++)
          acc[mt][nt] = __builtin_amdgcn_mfma_f32_16x16x32_bf16(af[mt], bfr[nt], acc[mt][nt], 0, 0, 0);
    }
  }

#pragma unroll
  for (int mt = 0; mt < 4; mt++) {
#pragma unroll
    for (int r = 0; r < 4; r++) {
      int row = m0 + wm + mt * 16 + quad * 4 + r;
#pragma unroll
      for (int nt = 0; nt < 2; nt++) {
        int col = n0 + wn + nt * 16 + lc;
        C[(size_t)row * 1024 + col] = acc[mt][nt][r] + bias[col];
      }
    }
  }
}

// ---------------- flash attention: DIRECT-GLOBAL K/V (no LDS, no barriers) ----------------
// Green-r5 base; single delta: K/V fragments loaded straight from global (L2-resident,
// r4-proven FETCH 12MB). kf = K[(kb+32*g64+ln)*1024 + 16*dc + 8*hi] (16B/lane);
// vbf = two 8B loads from Vt row (dg*32+ln) at token offsets 16m+4hi / 16m+8+4hi —
// bit-identical to what the swizzled-LDS path delivered (swizzle+unswizzle cancel).
// No stage/vmcnt/__syncthreads -> serial per-tile chain gone; occupancy VGPR-bound
// (launch_bounds(128,5) -> ~20 waves/CU vs r5's ~9). Grid/decode/mask/epilogue = r5.
__global__ __launch_bounds__(128, 5) void attn_kernel(const ushort* __restrict__ Qb,
                                                      const ushort* __restrict__ Kb,
                                                      const ushort* __restrict__ Vt,
                                                      float* __restrict__ O32,
                                                      float* __restrict__ L32) {
  const int bh = blockIdx.x, b = bh >> 4, h = bh & 15;
  // decode f -> (qi2 in [0,32), ci): heavy q-blocks (qi2=31) first
  int rem = (int)blockIdx.y, qi2 = 31;
  while (true) { int c = (qi2 + 8) >> 3; if (rem < c) break; rem -= c; qi2--; }
  const int ci = rem;
  const int t0 = ci * 8;
  const int t1 = min(t0 + 8, qi2 + 1);

  const int tid = threadIdx.x, lane = tid & 63, wid = tid >> 6;   // wid 0/1
  const int hi = lane >> 5, ln = lane & 31;
  const int qbw = qi2 * 64 + wid * 32;
  const int qg = qbw + ln;                    // this lane's q column

  const size_t kbase = (size_t)(b * 2048) * 1024 + h * 64;
  const size_t vbase = (size_t)bh * 131072;

  // Q B-fragments resident: 4 d-chunks of 16 (slot (hi,j) supplies d = dc*16 + 8*hi + j)
  bf16x8 qf[4];
  {
    const ushort* Qp = Qb + kbase + (size_t)qg * 1024 + hi * 8;
#pragma unroll
    for (int dc = 0; dc < 4; dc++)
      qf[dc] = *(const bf16x8*)(Qp + dc * 16);
  }

  f32x16 o_acc[2] = {};
  float l_own = 0.f;

  const ushort* Kp = Kb + kbase;              // token-major K plane, this (b,h)
  const ushort* Vp = Vt + vbase;              // [d 64][t 2048] plane, this bh

  for (int kt = t0; kt < t1; kt++) {
    const int kb = kt * 64;

#pragma unroll
    for (int g64 = 0; g64 < 2; g64++) {
      if (kb + g64 * 32 > qbw + 31) continue;  // half fully above diagonal (uniform)
      f32x16 s;
#pragma unroll
      for (int z = 0; z < 16; z++) s[z] = 0.f;
      // S^T(32 keys x 32 q) over d = 64 in 4 chunks of 16; K direct from global
      const ushort* krow = Kp + (size_t)(kb + g64 * 32 + ln) * 1024 + hi * 8;
      __builtin_amdgcn_s_setprio(1);
#pragma unroll
      for (int dc = 0; dc < 4; dc++) {
        bf16x8 kf = *(const bf16x8*)(krow + dc * 16);
        s = __builtin_amdgcn_mfma_f32_32x32x16_bf16(kf, qf[dc], s, 0, 0, 0);
      }
      __builtin_amdgcn_s_setprio(0);

      // softmax numerator: s[4g+j] = key_local 8g + 4hi + j (within this g64 half)
      unsigned U[8];
      const bool dmask = (kb + g64 * 32 + 31 > qbw);  // wave-uniform diagonal test
      if (dmask) {
        const int c = qg - kb - g64 * 32 - hi * 4;    // allowed iff g*8+j <= c
#pragma unroll
        for (int g = 0; g < 4; g++) {
          float e[4];
#pragma unroll
          for (int j = 0; j < 4; j++) {
            float sv = s[g * 4 + j];
            if (g * 8 + j > c) sv = -1e30f;
            e[j] = __builtin_amdgcn_exp2f(sv);
          }
          l_own += (e[0] + e[1]) + (e[2] + e[3]);
          union { float f; unsigned u; } f0{e[0]}, f1{e[1]}, f2{e[2]}, f3{e[3]};
          U[g * 2]     = __builtin_amdgcn_perm(f1.u + 0x8000u, f0.u + 0x8000u, 0x07060302u);
          U[g * 2 + 1] = __builtin_amdgcn_perm(f3.u + 0x8000u, f2.u + 0x8000u, 0x07060302u);
        }
      } else {
#pragma unroll
        for (int g = 0; g < 4; g++) {
          float e[4];
#pragma unroll
          for (int j = 0; j < 4; j++)
            e[j] = __builtin_amdgcn_exp2f(s[g * 4 + j]);
          l_own += (e[0] + e[1]) + (e[2] + e[3]);
          union { float f; unsigned u; } f0{e[0]}, f1{e[1]}, f2{e[2]}, f3{e[3]};
          U[g * 2]     = __builtin_amdgcn_perm(f1.u + 0x8000u, f0.u + 0x8000u, 0x07060302u);
          U[g * 2 + 1] = __builtin_amdgcn_perm(f3.u + 0x8000u, f2.u + 0x8000u, 0x07060302u);
        }
      }

      // O += P V, fragments m = 2*g64 + half; V direct from global (keymap as r3)
      __builtin_amdgcn_s_setprio(1);
#pragma unroll
      for (int half = 0; half < 2; half++) {
        const int m = g64 * 2 + half;
        bf16x8 pfrag;
#pragma unroll
        for (int w = 0; w < 4; w++) ((unsigned*)&pfrag)[w] = U[half * 4 + w];
#pragma unroll
        for (int dg = 0; dg < 2; dg++) {
          const ushort* vr = Vp + (size_t)(dg * 32 + ln) * 2048 + kb + 16 * m + 4 * hi;
          bf16x8 vbf;
          *(unsigned long long*)&vbf = *(const unsigned long long*)vr;        // t: 16m+4hi..+3
          *((unsigned long long*)&vbf + 1) = *(const unsigned long long*)(vr + 8); // +8..
          o_acc[dg] = __builtin_amdgcn_mfma_f32_32x32x16_bf16(pfrag, vbf, o_acc[dg], 0, 0, 0);
        }
      }
      __builtin_amdgcn_s_setprio(0);
    }
  }

  // l: combine hi halves (lane <-> lane^32 hold complementary key sets, same q)
  {
    float lt = l_own + __shfl_xor(l_own, 32);
    if (hi == 0) atomicAdd(&L32[(size_t)bh * 2048 + qg], lt);
  }
  // O partials: lane holds O[q = (r&3)+8*(r>>2)+4hi][dg*32+ln]
#pragma unroll
  for (int r = 0; r < 16; r++) {
    int q = qbw + (r & 3) + ((r >> 2) << 3) + hi * 4;
    size_t orow = ((size_t)(b * 2048) + q) * 1024 + h * 64 + ln;
    atomicAdd(&O32[orow], o_acc[0][r]);
    atomicAdd(&O32[orow + 32], o_acc[1][r]);
  }
}

// ---------------- normalize: O32/l -> bf16 attn_out ----------------
__global__ __launch_bounds__(256) void normalize_kernel(const float* __restrict__ O32,
                                                        const float* __restrict__ L32,
                                                        ushort* __restrict__ Out) {
  const int row = blockIdx.x;            // 0..4095  (b*2048 + t)
  const int tid = threadIdx.x;
  const int col = tid * 4;
  const int b = row >> 11, t = row & 2047, h = col >> 6;
  const float inv = 1.0f / L32[(size_t)(b * 16 + h) * 2048 + t];
  float4 o = ((const float4*)(O32 + (size_t)row * 1024))[tid];
  ushort4 u;
  u.x = f2bf(o.x * inv); u.y = f2bf(o.y * inv);
  u.z = f2bf(o.z * inv); u.w = f2bf(o.w * inv);
  ((ushort4*)(Out + (size_t)row * 1024))[tid] = u;
}

// ---------------- launcher ----------------
extern "C" void kernel_launch(void* const* d_in, const int* in_sizes, int n_in,
                              void* d_out, int out_size, void* d_ws, size_t ws_size,
                              hipStream_t stream) {
  const float* x  = (const float*)d_in[0];
  const float* Wq = (const float*)d_in[1];
  const float* Wk = (const float*)d_in[2];
  const float* Wv = (const float*)d_in[3];
  const float* Wo = (const float*)d_in[4];
  const float* bo = (const float*)d_in[5];
  float* out = (float*)d_out;

  char* ws = (char*)d_ws;
  ushort* xbf  = (ushort*)(ws);                  //  8 MB: x bf16 (dead after gemm_qkv)
  ushort* wcat = (ushort*)(ws + (8ull  << 20));  //  8 MB: Wcat bf16
  ushort* qkv  = (ushort*)(ws + (16ull << 20));  // 24 MB: Q | K | Vt planes
  ushort* Qp   = qkv;
  ushort* Kp   = qkv + (1ull << 22);
  ushort* Vt   = qkv + (2ull << 22);             // V written directly transposed
  float*  L32  = (float*)ws;                     // 256 KB over dead xbf
  float*  O32  = out;                            // d_out as fp32 accumulator scratch
  ushort* attn_out = Qp;                         // Q plane free after attn

  // cast x+weights, zero O32 (12288 blocks = 3M threads)
  cast_all<<<12288, 256, 0, stream>>>(x, Wq, Wk, Wv, Wo, xbf, wcat, (float4*)O32);

  // QKV = x @ Wcat[0:3072]^T; Q pre-scaled by 0.125*log2e; V transposed in epilogue via LDS
  gemm_qkv<<<dim3(24, 32), 256, 0, stream>>>(xbf, wcat, qkv, Vt);

  hipMemsetAsync(L32, 0, (size_t)32 * 2048 * 4, stream);

  attn_kernel<<<dim3(32, 80), 128, 0, stream>>>(Qp, Kp, Vt, O32, L32);

  normalize_kernel<<<4096, 256, 0, stream>>>(O32, L32, attn_out);

  // out = attn_out @ Wo^T + bo   (overwrites O32 scratch, stream-ordered)
  gemm_proj<<<dim3(16, 32), 256, 0, stream>>>(
      attn_out, wcat + (size_t)3072 * 1024, out, bo);
}

// Round 9
// 249.010 us; speedup vs baseline: 1.0684x; 1.0684x over previous
//
#include <hip/hip_runtime.h>
#include <math.h>

typedef __attribute__((ext_vector_type(8))) short bf16x8;
typedef __attribute__((ext_vector_type(4))) float f32x4;
typedef __attribute__((ext_vector_type(16))) float f32x16;

__device__ __forceinline__ ushort f2bf(float f) {
  union { float f; unsigned u; } v; v.f = f;
  return (ushort)((v.u + 0x8000u) >> 16);
}

// async global->LDS, 16B per lane. lds base wave-uniform; lane i lands at base + i*16B.
__device__ __forceinline__ void g2l16(const void* g, void* l) {
  __builtin_amdgcn_global_load_lds((const __attribute__((address_space(1))) unsigned*)g,
                                   (__attribute__((address_space(3))) unsigned*)l, 16, 0, 0);
}

// ---------------- merged cast + zero kernel ----------------
// idx [0,1M): x -> xbf.  [1M,2M): weights -> wcat (Wq scaled).  [2M,3M): zero O32.
__global__ __launch_bounds__(256) void cast_all(const float* __restrict__ x,
                                                const float* __restrict__ Wq,
                                                const float* __restrict__ Wk,
                                                const float* __restrict__ Wv,
                                                const float* __restrict__ Wo,
                                                ushort* __restrict__ xbf,
                                                ushort* __restrict__ wcat,
                                                float4* __restrict__ O32) {
  int i = blockIdx.x * 256 + threadIdx.x;
  if (i < 1048576) {
    float4 v = ((const float4*)x)[i];
    ushort4 u; u.x = f2bf(v.x); u.y = f2bf(v.y); u.z = f2bf(v.z); u.w = f2bf(v.w);
    ((ushort4*)xbf)[i] = u;
  } else if (i < 2097152) {
    int j = i - 1048576;
    int sel = j >> 18;
    const float* src = (sel == 0) ? Wq : (sel == 1) ? Wk : (sel == 2) ? Wv : Wo;
    float scale = (sel == 0) ? 0.125f * 1.44269504088896f : 1.0f;  // fold D^-0.5 * log2e
    float4 v = ((const float4*)src)[j & 0x3FFFF];
    ushort4 u;
    u.x = f2bf(v.x * scale); u.y = f2bf(v.y * scale);
    u.z = f2bf(v.z * scale); u.w = f2bf(v.w * scale);
    ((ushort4*)wcat)[j] = u;
  } else {
    O32[i - 2097152] = float4{0.f, 0.f, 0.f, 0.f};
  }
}

// ---------------- QKV GEMM: C = A @ B^T, 128x128, BK=32, dbuf ----------------
// Q/K planes token-major; V blocks write Vt[bh][d][t] via LDS transpose in the epilogue.
__global__ __launch_bounds__(256) void gemm_qkv(const ushort* __restrict__ A,
                                                const ushort* __restrict__ B,
                                                ushort* __restrict__ C3,
                                                ushort* __restrict__ Vt) {
  const int K = 1024;
  __shared__ __align__(16) ushort smem[17408];   // staging 32KB / transpose T[128][136]
  ushort* As = smem;           // [2][128*32]
  ushort* Bs = smem + 8192;    // [2][128*32]
  const int m0 = blockIdx.y * 128, n0 = blockIdx.x * 128;
  const int tid = threadIdx.x, lane = tid & 63, wid = tid >> 6;
  const int quad = lane >> 4, lc = lane & 15;
  const int lrow = lane >> 2, lcol = (lane & 3) * 8;
  const int wm = (wid >> 1) * 64, wn = (wid & 1) * 64;

  f32x4 acc[4][4] = {};

  auto stage = [&](int k0, int nb) {
    const ushort* Ag = A + (size_t)(m0 + wid * 32 + lrow) * K + k0 + lcol;
    g2l16(Ag, &As[nb * 4096 + wid * 1024]);
    g2l16(Ag + (size_t)16 * K, &As[nb * 4096 + wid * 1024 + 512]);
    const ushort* Bg = B + (size_t)(n0 + wid * 32 + lrow) * K + k0 + lcol;
    g2l16(Bg, &Bs[nb * 4096 + wid * 1024]);
    g2l16(Bg + (size_t)16 * K, &Bs[nb * 4096 + wid * 1024 + 512]);
  };

  stage(0, 0);
  for (int k0 = 0; k0 < K; k0 += 32) {
    const int nb = (k0 >> 5) & 1;
    __syncthreads();
    if (k0 + 32 < K) stage(k0 + 32, nb ^ 1);

    bf16x8 af[4], bfr[4];
#pragma unroll
    for (int t = 0; t < 4; t++)
      af[t] = *(const bf16x8*)&As[nb * 4096 + (wm + t * 16 + lc) * 32 + quad * 8];
#pragma unroll
    for (int t = 0; t < 4; t++)
      bfr[t] = *(const bf16x8*)&Bs[nb * 4096 + (wn + t * 16 + lc) * 32 + quad * 8];
#pragma unroll
    for (int mt = 0; mt < 4; mt++)
#pragma unroll
      for (int nt = 0; nt < 4; nt++)
        acc[mt][nt] = __builtin_amdgcn_mfma_f32_16x16x32_bf16(af[mt], bfr[nt], acc[mt][nt], 0, 0, 0);
  }

  const int sel = n0 >> 10;   // 0=Q, 1=K, 2=V (block-uniform)
  if (sel < 2) {
#pragma unroll
    for (int mt = 0; mt < 4; mt++) {
#pragma unroll
      for (int r = 0; r < 4; r++) {
        int row = m0 + wm + mt * 16 + quad * 4 + r;
#pragma unroll
        for (int nt = 0; nt < 4; nt++) {
          int col = n0 + wn + nt * 16 + lc;
          size_t dst = ((size_t)sel << 22) + (size_t)row * 1024 + (col & 1023);
          C3[dst] = f2bf(acc[mt][nt][r]);
        }
      }
    }
  } else {
    // transpose through LDS: T[d_local 128][token_local 128], pitch 136
    __syncthreads();
#pragma unroll
    for (int mt = 0; mt < 4; mt++)
#pragma unroll
      for (int r = 0; r < 4; r++) {
        int tl = wm + mt * 16 + quad * 4 + r;
#pragma unroll
        for (int nt = 0; nt < 4; nt++)
          smem[(wn + nt * 16 + lc) * 136 + tl] = f2bf(acc[mt][nt][r]);
      }
    __syncthreads();
    const int hd0 = n0 - 2048, b = m0 >> 11, t_base = m0 & 2047;
#pragma unroll
    for (int i = 0; i < 8; i++) {
      int idx = i * 256 + tid;
      int dl = idx >> 4, tc = (idx & 15) * 8;
      uint4 v = *(const uint4*)&smem[dl * 136 + tc];
      int hd = hd0 + dl;
      *(uint4*)(Vt + (size_t)(b * 16 + (hd >> 6)) * 131072 +
                (size_t)(hd & 63) * 2048 + t_base + tc) = v;
    }
  }
}

// ---------------- proj GEMM: out[4096][1024] = attn_out @ Wo^T + bo, BK=64 ----------------
__global__ __launch_bounds__(256) void gemm_proj(const ushort* __restrict__ A,
                                                 const ushort* __restrict__ B,
                                                 float* __restrict__ C,
                                                 const float* __restrict__ bias) {
  const int K = 1024;
  __shared__ __align__(16) ushort As[2][2][128 * 32];
  __shared__ __align__(16) ushort Bs[2][2][64 * 32];
  const int m0 = blockIdx.y * 128, n0 = blockIdx.x * 64;
  const int tid = threadIdx.x, lane = tid & 63, wid = tid >> 6;
  const int quad = lane >> 4, lc = lane & 15;
  const int lrow = lane >> 2, lcol = (lane & 3) * 8;
  const int wm = (wid >> 1) * 64, wn = (wid & 1) * 32;

  f32x4 acc[4][2] = {};

  auto stage = [&](int k0, int nb) {
    const ushort* Ag = A + (size_t)(m0 + wid * 32 + lrow) * K + k0 + lcol;
    g2l16(Ag,                       &As[nb][0][wid * 1024]);
    g2l16(Ag + (size_t)16 * K,      &As[nb][0][wid * 1024 + 512]);
    g2l16(Ag + 32,                  &As[nb][1][wid * 1024]);
    g2l16(Ag + (size_t)16 * K + 32, &As[nb][1][wid * 1024 + 512]);
    const ushort* Bg = B + (size_t)(n0 + wid * 16 + lrow) * K + k0 + lcol;
    g2l16(Bg,      &Bs[nb][0][wid * 512]);
    g2l16(Bg + 32, &Bs[nb][1][wid * 512]);
  };

  stage(0, 0);
  for (int k0 = 0; k0 < K; k0 += 64) {
    const int nb = (k0 >> 6) & 1;
    __syncthreads();
    if (k0 + 64 < K) stage(k0 + 64, nb ^ 1);

#pragma unroll
    for (int ks = 0; ks < 2; ks++) {
      bf16x8 af[4], bfr[2];
#pragma unroll
      for (int t = 0; t < 4; t++)
        af[t] = *(const bf16x8*)&As[nb][ks][(wm + t * 16 + lc) * 32 + quad * 8];
#pragma unroll
      for (int t = 0; t < 2; t++)
        bfr[t] = *(const bf16x8*)&Bs[nb][ks][(wn + t * 16 + lc) * 32 + quad * 8];
#pragma unroll
      for (int mt = 0; mt < 4; mt++)
#pragma unroll
        for (int nt = 0; nt < 2; nt++)
          acc[mt][nt] = __builtin_amdgcn_mfma_f32_16x16x32_bf16(af[mt], bfr[nt], acc[mt][nt], 0, 0, 0);
    }
  }

#pragma unroll
  for (int mt = 0; mt < 4; mt++) {
#pragma unroll
    for (int r = 0; r < 4; r++) {
      int row = m0 + wm + mt * 16 + quad * 4 + r;
#pragma unroll
      for (int nt = 0; nt < 2; nt++) {
        int col = n0 + wn + nt * 16 + lc;
        C[(size_t)row * 1024 + col] = acc[mt][nt][r] + bias[col];
      }
    }
  }
}

// ---------------- flash attention: 2-wave blocks, T14 register-prefetch staging ----------
// Green-r5 base (52us); single delta: staging is now global->REG (issued one full tile
// EARLY, latency hides under compute) then ds_write->LDS after the post-compute barrier.
// r8 proved direct-global (no pipeline) is 2.3x worse; r5's in-tile vmcnt(0) gave loads
// zero distance. This gives them a whole compute phase (~800cy). LDS layout/addresses
// byte-identical to r5's global_load_lds (lane -> i*1024 + lane*16, pre-swizzled src).
__global__ __launch_bounds__(128, 4) void attn_kernel(const ushort* __restrict__ Qb,
                                                      const ushort* __restrict__ Kb,
                                                      const ushort* __restrict__ Vt,
                                                      float* __restrict__ O32,
                                                      float* __restrict__ L32) {
  __shared__ __align__(16) ushort Ks[4096];   // [key 64][d 64] swizzled, 8KB
  __shared__ __align__(16) ushort Vs[4096];   // [d 64][t 64]  swizzled, 8KB

  const int bh = blockIdx.x, b = bh >> 4, h = bh & 15;
  // decode f -> (qi2 in [0,32), ci): heavy q-blocks (qi2=31) first
  int rem = (int)blockIdx.y, qi2 = 31;
  while (true) { int c = (qi2 + 8) >> 3; if (rem < c) break; rem -= c; qi2--; }
  const int ci = rem;
  const int t0 = ci * 8;
  const int t1 = min(t0 + 8, qi2 + 1);

  const int tid = threadIdx.x, lane = tid & 63, wid = tid >> 6;   // wid 0/1
  const int hi = lane >> 5, ln = lane & 31;
  const int qbw = qi2 * 64 + wid * 32;
  const int qg = qbw + ln;                    // this lane's q column

  const size_t kbase = (size_t)(b * 2048) * 1024 + h * 64;
  const size_t vbase = (size_t)bh * 131072;

  // Q B-fragments resident: 4 d-chunks of 16 (slot (hi,j) supplies d = dc*16 + 8*hi + j)
  bf16x8 qf[4];
  {
    const ushort* Qp = Qb + kbase + (size_t)qg * 1024 + hi * 8;
#pragma unroll
    for (int dc = 0; dc < 4; dc++)
      qf[dc] = *(const bf16x8*)(Qp + dc * 16);
  }

  f32x16 o_acc[2] = {};
  float l_own = 0.f;

  // staging addresses (identical to r5's g2l16 mapping): wave0 -> K, wave1 -> V.
  // lane covers row i*8 + (lane>>3), 8-elem group (lane&7); source group pre-XOR'd
  // by row&7 so LDS stays linear and reads unswizzle with sx.
  const int krow = lane >> 3, kcol = lane & 7;
  const int dsw = (kcol ^ krow) << 3;          // swizzled element offset within row

  uint4 rg[8];                                 // in-flight tile (32 VGPR)
  auto issue = [&](int kb) {
    if (wid == 0) {
      const ushort* gK = Kb + kbase + (size_t)(kb + krow) * 1024 + dsw;
#pragma unroll
      for (int i = 0; i < 8; i++)
        rg[i] = *(const uint4*)(gK + (size_t)(i * 8) * 1024);
    } else {
      const ushort* gV = Vt + vbase + (size_t)krow * 2048 + kb + dsw;
#pragma unroll
      for (int i = 0; i < 8; i++)
        rg[i] = *(const uint4*)(gV + (size_t)(i * 8) * 2048);
    }
  };
  auto commit = [&]() {
    ushort* dst = (wid == 0) ? Ks : Vs;
#pragma unroll
    for (int i = 0; i < 8; i++)
      *(uint4*)(dst + i * 512 + lane * 8) = rg[i];   // byte: i*1024 + lane*16 (= g2l16)
  };

  const int sx = ln & 7;                       // row&7 for this lane's reads

  issue(t0 * 64);
  commit();                                    // compiler waits loads before ds_write
  __syncthreads();

  for (int kt = t0; kt < t1; kt++) {
    const int kb = kt * 64;
    if (kt + 1 < t1) issue((kt + 1) * 64);     // loads fly during this tile's compute

#pragma unroll
    for (int g64 = 0; g64 < 2; g64++) {
      if (kb + g64 * 32 > qbw + 31) continue;  // half fully above diagonal (uniform)
      f32x16 s;
#pragma unroll
      for (int z = 0; z < 16; z++) s[z] = 0.f;
      // S^T(32 keys x 32 q) over d = 64 in 4 chunks of 16
      __builtin_amdgcn_s_setprio(1);
#pragma unroll
      for (int dc = 0; dc < 4; dc++) {
        bf16x8 kf = *(const bf16x8*)&Ks[(g64 * 32 + ln) * 64 + (((dc * 2 + hi) ^ sx) << 3)];
        s = __builtin_amdgcn_mfma_f32_32x32x16_bf16(kf, qf[dc], s, 0, 0, 0);
      }
      __builtin_amdgcn_s_setprio(0);

      // softmax numerator: s[4g+j] = key_local 8g + 4hi + j (within this g64 half)
      unsigned U[8];
      const bool dmask = (kb + g64 * 32 + 31 > qbw);  // wave-uniform diagonal test
      if (dmask) {
        const int c = qg - kb - g64 * 32 - hi * 4;    // allowed iff g*8+j <= c
#pragma unroll
        for (int g = 0; g < 4; g++) {
          float e[4];
#pragma unroll
          for (int j = 0; j < 4; j++) {
            float sv = s[g * 4 + j];
            if (g * 8 + j > c) sv = -1e30f;
            e[j] = __builtin_amdgcn_exp2f(sv);
          }
          l_own += (e[0] + e[1]) + (e[2] + e[3]);
          union { float f; unsigned u; } f0{e[0]}, f1{e[1]}, f2{e[2]}, f3{e[3]};
          U[g * 2]     = __builtin_amdgcn_perm(f1.u + 0x8000u, f0.u + 0x8000u, 0x07060302u);
          U[g * 2 + 1] = __builtin_amdgcn_perm(f3.u + 0x8000u, f2.u + 0x8000u, 0x07060302u);
        }
      } else {
#pragma unroll
        for (int g = 0; g < 4; g++) {
          float e[4];
#pragma unroll
          for (int j = 0; j < 4; j++)
            e[j] = __builtin_amdgcn_exp2f(s[g * 4 + j]);
          l_own += (e[0] + e[1]) + (e[2] + e[3]);
          union { float f; unsigned u; } f0{e[0]}, f1{e[1]}, f2{e[2]}, f3{e[3]};
          U[g * 2]     = __builtin_amdgcn_perm(f1.u + 0x8000u, f0.u + 0x8000u, 0x07060302u);
          U[g * 2 + 1] = __builtin_amdgcn_perm(f3.u + 0x8000u, f2.u + 0x8000u, 0x07060302u);
        }
      }

      // O += P V, fragments m = 2*g64 + half; keymap as r3 (no cross-lane P movement)
      __builtin_amdgcn_s_setprio(1);
#pragma unroll
      for (int half = 0; half < 2; half++) {
        const int m = g64 * 2 + half;
        bf16x8 pfrag;
#pragma unroll
        for (int w = 0; w < 4; w++) ((unsigned*)&pfrag)[w] = U[half * 4 + w];
#pragma unroll
        for (int dg = 0; dg < 2; dg++) {
          const ushort* vrow = &Vs[(dg * 32 + ln) * 64];
          bf16x8 vbf;
          *(unsigned long long*)&vbf =
              *(const unsigned long long*)&vrow[(((2 * m) ^ sx) << 3) + 4 * hi];
          *((unsigned long long*)&vbf + 1) =
              *(const unsigned long long*)&vrow[(((2 * m + 1) ^ sx) << 3) + 4 * hi];
          o_acc[dg] = __builtin_amdgcn_mfma_f32_32x32x16_bf16(pfrag, vbf, o_acc[dg], 0, 0, 0);
        }
      }
      __builtin_amdgcn_s_setprio(0);
    }

    __syncthreads();                           // all lanes done reading Ks/Vs
    if (kt + 1 < t1) {
      commit();                                // ds_write next tile (waits its vmcnt)
      __syncthreads();                         // LDS ready for next iteration
    }
  }

  // l: combine hi halves (lane <-> lane^32 hold complementary key sets, same q)
  {
    float lt = l_own + __shfl_xor(l_own, 32);
    if (hi == 0) atomicAdd(&L32[(size_t)bh * 2048 + qg], lt);
  }
  // O partials: lane holds O[q = (r&3)+8*(r>>2)+4hi][dg*32+ln]
#pragma unroll
  for (int r = 0; r < 16; r++) {
    int q = qbw + (r & 3) + ((r >> 2) << 3) + hi * 4;
    size_t orow = ((size_t)(b * 2048) + q) * 1024 + h * 64 + ln;
    atomicAdd(&O32[orow], o_acc[0][r]);
    atomicAdd(&O32[orow + 32], o_acc[1][r]);
  }
}

// ---------------- normalize: O32/l -> bf16 attn_out ----------------
__global__ __launch_bounds__(256) void normalize_kernel(const float* __restrict__ O32,
                                                        const float* __restrict__ L32,
                                                        ushort* __restrict__ Out) {
  const int row = blockIdx.x;            // 0..4095  (b*2048 + t)
  const int tid = threadIdx.x;
  const int col = tid * 4;
  const int b = row >> 11, t = row & 2047, h = col >> 6;
  const float inv = 1.0f / L32[(size_t)(b * 16 + h) * 2048 + t];
  float4 o = ((const float4*)(O32 + (size_t)row * 1024))[tid];
  ushort4 u;
  u.x = f2bf(o.x * inv); u.y = f2bf(o.y * inv);
  u.z = f2bf(o.z * inv); u.w = f2bf(o.w * inv);
  ((ushort4*)(Out + (size_t)row * 1024))[tid] = u;
}

// ---------------- launcher ----------------
extern "C" void kernel_launch(void* const* d_in, const int* in_sizes, int n_in,
                              void* d_out, int out_size, void* d_ws, size_t ws_size,
                              hipStream_t stream) {
  const float* x  = (const float*)d_in[0];
  const float* Wq = (const float*)d_in[1];
  const float* Wk = (const float*)d_in[2];
  const float* Wv = (const float*)d_in[3];
  const float* Wo = (const float*)d_in[4];
  const float* bo = (const float*)d_in[5];
  float* out = (float*)d_out;

  char* ws = (char*)d_ws;
  ushort* xbf  = (ushort*)(ws);                  //  8 MB: x bf16 (dead after gemm_qkv)
  ushort* wcat = (ushort*)(ws + (8ull  << 20));  //  8 MB: Wcat bf16
  ushort* qkv  = (ushort*)(ws + (16ull << 20));  // 24 MB: Q | K | Vt planes
  ushort* Qp   = qkv;
  ushort* Kp   = qkv + (1ull << 22);
  ushort* Vt   = qkv + (2ull << 22);             // V written directly transposed
  float*  L32  = (float*)ws;                     // 256 KB over dead xbf
  float*  O32  = out;                            // d_out as fp32 accumulator scratch
  ushort* attn_out = Qp;                         // Q plane free after attn

  // cast x+weights, zero O32 (12288 blocks = 3M threads)
  cast_all<<<12288, 256, 0, stream>>>(x, Wq, Wk, Wv, Wo, xbf, wcat, (float4*)O32);

  // QKV = x @ Wcat[0:3072]^T; Q pre-scaled by 0.125*log2e; V transposed in epilogue via LDS
  gemm_qkv<<<dim3(24, 32), 256, 0, stream>>>(xbf, wcat, qkv, Vt);

  hipMemsetAsync(L32, 0, (size_t)32 * 2048 * 4, stream);

  attn_kernel<<<dim3(32, 80), 128, 0, stream>>>(Qp, Kp, Vt, O32, L32);

  normalize_kernel<<<4096, 256, 0, stream>>>(O32, L32, attn_out);

  // out = attn_out @ Wo^T + bo   (overwrites O32 scratch, stream-ordered)
  gemm_proj<<<dim3(16, 32), 256, 0, stream>>>(
      attn_out, wcat + (size_t)3072 * 1024, out, bo);
}

// Round 10
// 192.161 us; speedup vs baseline: 1.3845x; 1.2958x over previous
//
#include <hip/hip_runtime.h>
#include <math.h>

typedef __attribute__((ext_vector_type(8))) short bf16x8;
typedef __attribute__((ext_vector_type(4))) float f32x4;
typedef __attribute__((ext_vector_type(16))) float f32x16;

__device__ __forceinline__ ushort f2bf(float f) {
  union { float f; unsigned u; } v; v.f = f;
  return (ushort)((v.u + 0x8000u) >> 16);
}

// async global->LDS, 16B per lane. lds base wave-uniform; lane i lands at base + i*16B.
__device__ __forceinline__ void g2l16(const void* g, void* l) {
  __builtin_amdgcn_global_load_lds((const __attribute__((address_space(1))) unsigned*)g,
                                   (__attribute__((address_space(3))) unsigned*)l, 16, 0, 0);
}

// ---------------- merged cast + zero kernel ----------------
// idx [0,1M): x -> xbf.  [1M,2M): weights -> wcat (Wq scaled).  [2M,3M): zero O32.
__global__ __launch_bounds__(256) void cast_all(const float* __restrict__ x,
                                                const float* __restrict__ Wq,
                                                const float* __restrict__ Wk,
                                                const float* __restrict__ Wv,
                                                const float* __restrict__ Wo,
                                                ushort* __restrict__ xbf,
                                                ushort* __restrict__ wcat,
                                                float4* __restrict__ O32) {
  int i = blockIdx.x * 256 + threadIdx.x;
  if (i < 1048576) {
    float4 v = ((const float4*)x)[i];
    ushort4 u; u.x = f2bf(v.x); u.y = f2bf(v.y); u.z = f2bf(v.z); u.w = f2bf(v.w);
    ((ushort4*)xbf)[i] = u;
  } else if (i < 2097152) {
    int j = i - 1048576;
    int sel = j >> 18;
    const float* src = (sel == 0) ? Wq : (sel == 1) ? Wk : (sel == 2) ? Wv : Wo;
    float scale = (sel == 0) ? 0.125f * 1.44269504088896f : 1.0f;  // fold D^-0.5 * log2e
    float4 v = ((const float4*)src)[j & 0x3FFFF];
    ushort4 u;
    u.x = f2bf(v.x * scale); u.y = f2bf(v.y * scale);
    u.z = f2bf(v.z * scale); u.w = f2bf(v.w * scale);
    ((ushort4*)wcat)[j] = u;
  } else {
    O32[i - 2097152] = float4{0.f, 0.f, 0.f, 0.f};
  }
}

// ---------------- QKV GEMM: C = A @ B^T, 128x128, BK=32, dbuf ----------------
// Q/K planes token-major; V blocks write Vt[bh][d][t] via LDS transpose in the epilogue.
__global__ __launch_bounds__(256) void gemm_qkv(const ushort* __restrict__ A,
                                                const ushort* __restrict__ B,
                                                ushort* __restrict__ C3,
                                                ushort* __restrict__ Vt) {
  const int K = 1024;
  __shared__ __align__(16) ushort smem[17408];   // staging 32KB / transpose T[128][136]
  ushort* As = smem;           // [2][128*32]
  ushort* Bs = smem + 8192;    // [2][128*32]
  const int m0 = blockIdx.y * 128, n0 = blockIdx.x * 128;
  const int tid = threadIdx.x, lane = tid & 63, wid = tid >> 6;
  const int quad = lane >> 4, lc = lane & 15;
  const int lrow = lane >> 2, lcol = (lane & 3) * 8;
  const int wm = (wid >> 1) * 64, wn = (wid & 1) * 64;

  f32x4 acc[4][4] = {};

  auto stage = [&](int k0, int nb) {
    const ushort* Ag = A + (size_t)(m0 + wid * 32 + lrow) * K + k0 + lcol;
    g2l16(Ag, &As[nb * 4096 + wid * 1024]);
    g2l16(Ag + (size_t)16 * K, &As[nb * 4096 + wid * 1024 + 512]);
    const ushort* Bg = B + (size_t)(n0 + wid * 32 + lrow) * K + k0 + lcol;
    g2l16(Bg, &Bs[nb * 4096 + wid * 1024]);
    g2l16(Bg + (size_t)16 * K, &Bs[nb * 4096 + wid * 1024 + 512]);
  };

  stage(0, 0);
  for (int k0 = 0; k0 < K; k0 += 32) {
    const int nb = (k0 >> 5) & 1;
    __syncthreads();
    if (k0 + 32 < K) stage(k0 + 32, nb ^ 1);

    bf16x8 af[4], bfr[4];
#pragma unroll
    for (int t = 0; t < 4; t++)
      af[t] = *(const bf16x8*)&As[nb * 4096 + (wm + t * 16 + lc) * 32 + quad * 8];
#pragma unroll
    for (int t = 0; t < 4; t++)
      bfr[t] = *(const bf16x8*)&Bs[nb * 4096 + (wn + t * 16 + lc) * 32 + quad * 8];
#pragma unroll
    for (int mt = 0; mt < 4; mt++)
#pragma unroll
      for (int nt = 0; nt < 4; nt++)
        acc[mt][nt] = __builtin_amdgcn_mfma_f32_16x16x32_bf16(af[mt], bfr[nt], acc[mt][nt], 0, 0, 0);
  }

  const int sel = n0 >> 10;   // 0=Q, 1=K, 2=V (block-uniform)
  if (sel < 2) {
#pragma unroll
    for (int mt = 0; mt < 4; mt++) {
#pragma unroll
      for (int r = 0; r < 4; r++) {
        int row = m0 + wm + mt * 16 + quad * 4 + r;
#pragma unroll
        for (int nt = 0; nt < 4; nt++) {
          int col = n0 + wn + nt * 16 + lc;
          size_t dst = ((size_t)sel << 22) + (size_t)row * 1024 + (col & 1023);
          C3[dst] = f2bf(acc[mt][nt][r]);
        }
      }
    }
  } else {
    // transpose through LDS: T[d_local 128][token_local 128], pitch 136
    __syncthreads();
#pragma unroll
    for (int mt = 0; mt < 4; mt++)
#pragma unroll
      for (int r = 0; r < 4; r++) {
        int tl = wm + mt * 16 + quad * 4 + r;
#pragma unroll
        for (int nt = 0; nt < 4; nt++)
          smem[(wn + nt * 16 + lc) * 136 + tl] = f2bf(acc[mt][nt][r]);
      }
    __syncthreads();
    const int hd0 = n0 - 2048, b = m0 >> 11, t_base = m0 & 2047;
#pragma unroll
    for (int i = 0; i < 8; i++) {
      int idx = i * 256 + tid;
      int dl = idx >> 4, tc = (idx & 15) * 8;
      uint4 v = *(const uint4*)&smem[dl * 136 + tc];
      int hd = hd0 + dl;
      *(uint4*)(Vt + (size_t)(b * 16 + (hd >> 6)) * 131072 +
                (size_t)(hd & 63) * 2048 + t_base + tc) = v;
    }
  }
}

// ---------------- proj GEMM: out[4096][1024] = attn_out @ Wo^T + bo, BK=64 ----------------
__global__ __launch_bounds__(256) void gemm_proj(const ushort* __restrict__ A,
                                                 const ushort* __restrict__ B,
                                                 float* __restrict__ C,
                                                 const float* __restrict__ bias) {
  const int K = 1024;
  __shared__ __align__(16) ushort As[2][2][128 * 32];
  __shared__ __align__(16) ushort Bs[2][2][64 * 32];
  const int m0 = blockIdx.y * 128, n0 = blockIdx.x * 64;
  const int tid = threadIdx.x, lane = tid & 63, wid = tid >> 6;
  const int quad = lane >> 4, lc = lane & 15;
  const int lrow = lane >> 2, lcol = (lane & 3) * 8;
  const int wm = (wid >> 1) * 64, wn = (wid & 1) * 32;

  f32x4 acc[4][2] = {};

  auto stage = [&](int k0, int nb) {
    const ushort* Ag = A + (size_t)(m0 + wid * 32 + lrow) * K + k0 + lcol;
    g2l16(Ag,                       &As[nb][0][wid * 1024]);
    g2l16(Ag + (size_t)16 * K,      &As[nb][0][wid * 1024 + 512]);
    g2l16(Ag + 32,                  &As[nb][1][wid * 1024]);
    g2l16(Ag + (size_t)16 * K + 32, &As[nb][1][wid * 1024 + 512]);
    const ushort* Bg = B + (size_t)(n0 + wid * 16 + lrow) * K + k0 + lcol;
    g2l16(Bg,      &Bs[nb][0][wid * 512]);
    g2l16(Bg + 32, &Bs[nb][1][wid * 512]);
  };

  stage(0, 0);
  for (int k0 = 0; k0 < K; k0 += 64) {
    const int nb = (k0 >> 6) & 1;
    __syncthreads();
    if (k0 + 64 < K) stage(k0 + 64, nb ^ 1);

#pragma unroll
    for (int ks = 0; ks < 2; ks++) {
      bf16x8 af[4], bfr[2];
#pragma unroll
      for (int t = 0; t < 4; t++)
        af[t] = *(const bf16x8*)&As[nb][ks][(wm + t * 16 + lc) * 32 + quad * 8];
#pragma unroll
      for (int t = 0; t < 2; t++)
        bfr[t] = *(const bf16x8*)&Bs[nb][ks][(wn + t * 16 + lc) * 32 + quad * 8];
#pragma unroll
      for (int mt = 0; mt < 4; mt++)
#pragma unroll
        for (int nt = 0; nt < 2; nt++)
          acc[mt][nt] = __builtin_amdgcn_mfma_f32_16x16x32_bf16(af[mt], bfr[nt], acc[mt][nt], 0, 0, 0);
    }
  }

#pragma unroll
  for (int mt = 0; mt < 4; mt++) {
#pragma unroll
    for (int r = 0; r < 4; r++) {
      int row = m0 + wm + mt * 16 + quad * 4 + r;
#pragma unroll
      for (int nt = 0; nt < 2; nt++) {
        int col = n0 + wn + nt * 16 + lc;
        C[(size_t)row * 1024 + col] = acc[mt][nt][r] + bias[col];
      }
    }
  }
}

// ---------------- flash attention: T14 staging, spill-proof (named regs, uniform role) ---
// r9's register-prefetch spilled rg[8] to scratch (WRITE 51->272MB, VGPR 60): divergent
// lambdas + array defeated regalloc. Fix: hoist the wave-role branch to ONE uniform
// pointer/stride selection; ISSUE/COMMIT are straight-line with 8 NAMED uint4 regs;
// launch_bounds(128,3) gives ~170 VGPR headroom (live set ~130). sched_barrier(0)
// after ISSUE pins loads above compute so they fly under the tile's MFMA+softmax.
// All math/addresses byte-identical to green r5/r9.
__global__ __launch_bounds__(128, 3) void attn_kernel(const ushort* __restrict__ Qb,
                                                      const ushort* __restrict__ Kb,
                                                      const ushort* __restrict__ Vt,
                                                      float* __restrict__ O32,
                                                      float* __restrict__ L32) {
  __shared__ __align__(16) ushort Ks[4096];   // [key 64][d 64] swizzled, 8KB
  __shared__ __align__(16) ushort Vs[4096];   // [d 64][t 64]  swizzled, 8KB

  const int bh = blockIdx.x, b = bh >> 4, h = bh & 15;
  // decode f -> (qi2 in [0,32), ci): heavy q-blocks (qi2=31) first
  int rem = (int)blockIdx.y, qi2 = 31;
  while (true) { int c = (qi2 + 8) >> 3; if (rem < c) break; rem -= c; qi2--; }
  const int ci = rem;
  const int t0 = ci * 8;
  const int t1 = min(t0 + 8, qi2 + 1);

  const int tid = threadIdx.x, lane = tid & 63, wid = tid >> 6;   // wid 0/1
  const int hi = lane >> 5, ln = lane & 31;
  const int qbw = qi2 * 64 + wid * 32;
  const int qg = qbw + ln;                    // this lane's q column

  const size_t kbase = (size_t)(b * 2048) * 1024 + h * 64;
  const size_t vbase = (size_t)bh * 131072;

  // Q B-fragments resident: 4 d-chunks of 16 (slot (hi,j) supplies d = dc*16 + 8*hi + j)
  bf16x8 qf[4];
  {
    const ushort* Qp = Qb + kbase + (size_t)qg * 1024 + hi * 8;
#pragma unroll
    for (int dc = 0; dc < 4; dc++)
      qf[dc] = *(const bf16x8*)(Qp + dc * 16);
  }

  f32x16 o_acc[2] = {};
  float l_own = 0.f;

  // staging (r5 g2l16 address map): wave0 -> K tile, wave1 -> V tile. lane covers
  // row i*8 + (lane>>3), 8-elem group (lane&7), source group pre-XOR'd by row&7.
  // Role hoisted to uniform pointer/stride so ISSUE/COMMIT are branch-free.
  const int krow = lane >> 3, kcol = lane & 7;
  const int dsw = (kcol ^ krow) << 3;          // swizzled element offset within row
  const bool isK = (wid == 0);
  const ushort* gsrc0 = isK ? (Kb + kbase + (size_t)krow * 1024 + dsw)
                            : (Vt + vbase + (size_t)krow * 2048 + dsw);
  const size_t rstride = isK ? (size_t)8 * 1024 : (size_t)8 * 2048;  // 8 rows down
  const size_t tmul = isK ? (size_t)1024 : (size_t)1;                // per-kb offset
  ushort* ldst = isK ? Ks : Vs;

  uint4 rg0, rg1, rg2, rg3, rg4, rg5, rg6, rg7;   // in-flight tile (named, 32 VGPR)
#define ATTN_ISSUE(KB) do { \
    const ushort* gp_ = gsrc0 + (size_t)(KB) * tmul; \
    rg0 = *(const uint4*)(gp_);                rg1 = *(const uint4*)(gp_ + rstride); \
    rg2 = *(const uint4*)(gp_ + 2 * rstride);  rg3 = *(const uint4*)(gp_ + 3 * rstride); \
    rg4 = *(const uint4*)(gp_ + 4 * rstride);  rg5 = *(const uint4*)(gp_ + 5 * rstride); \
    rg6 = *(const uint4*)(gp_ + 6 * rstride);  rg7 = *(const uint4*)(gp_ + 7 * rstride); \
  } while (0)
#define ATTN_COMMIT() do { \
    ushort* dp_ = ldst + lane * 8; \
    *(uint4*)(dp_)        = rg0;  *(uint4*)(dp_ + 512)  = rg1; \
    *(uint4*)(dp_ + 1024) = rg2;  *(uint4*)(dp_ + 1536) = rg3; \
    *(uint4*)(dp_ + 2048) = rg4;  *(uint4*)(dp_ + 2560) = rg5; \
    *(uint4*)(dp_ + 3072) = rg6;  *(uint4*)(dp_ + 3584) = rg7; \
  } while (0)

  const int sx = ln & 7;                       // row&7 for this lane's reads

  ATTN_ISSUE(t0 * 64);
  ATTN_COMMIT();                               // compiler waits loads before ds_write
  __syncthreads();

  for (int kt = t0; kt < t1; kt++) {
    const int kb = kt * 64;
    if (kt + 1 < t1) {
      ATTN_ISSUE(kb + 64);                     // loads fly during this tile's compute
      __builtin_amdgcn_sched_barrier(0);       // keep issue above the MFMA cluster
    }

#pragma unroll
    for (int g64 = 0; g64 < 2; g64++) {
      if (kb + g64 * 32 > qbw + 31) continue;  // half fully above diagonal (uniform)
      f32x16 s;
#pragma unroll
      for (int z = 0; z < 16; z++) s[z] = 0.f;
      // S^T(32 keys x 32 q) over d = 64 in 4 chunks of 16
      __builtin_amdgcn_s_setprio(1);
#pragma unroll
      for (int dc = 0; dc < 4; dc++) {
        bf16x8 kf = *(const bf16x8*)&Ks[(g64 * 32 + ln) * 64 + (((dc * 2 + hi) ^ sx) << 3)];
        s = __builtin_amdgcn_mfma_f32_32x32x16_bf16(kf, qf[dc], s, 0, 0, 0);
      }
      __builtin_amdgcn_s_setprio(0);

      // softmax numerator: s[4g+j] = key_local 8g + 4hi + j (within this g64 half)
      unsigned U[8];
      const bool dmask = (kb + g64 * 32 + 31 > qbw);  // wave-uniform diagonal test
      if (dmask) {
        const int c = qg - kb - g64 * 32 - hi * 4;    // allowed iff g*8+j <= c
#pragma unroll
        for (int g = 0; g < 4; g++) {
          float e[4];
#pragma unroll
          for (int j = 0; j < 4; j++) {
            float sv = s[g * 4 + j];
            if (g * 8 + j > c) sv = -1e30f;
            e[j] = __builtin_amdgcn_exp2f(sv);
          }
          l_own += (e[0] + e[1]) + (e[2] + e[3]);
          union { float f; unsigned u; } f0{e[0]}, f1{e[1]}, f2{e[2]}, f3{e[3]};
          U[g * 2]     = __builtin_amdgcn_perm(f1.u + 0x8000u, f0.u + 0x8000u, 0x07060302u);
          U[g * 2 + 1] = __builtin_amdgcn_perm(f3.u + 0x8000u, f2.u + 0x8000u, 0x07060302u);
        }
      } else {
#pragma unroll
        for (int g = 0; g < 4; g++) {
          float e[4];
#pragma unroll
          for (int j = 0; j < 4; j++)
            e[j] = __builtin_amdgcn_exp2f(s[g * 4 + j]);
          l_own += (e[0] + e[1]) + (e[2] + e[3]);
          union { float f; unsigned u; } f0{e[0]}, f1{e[1]}, f2{e[2]}, f3{e[3]};
          U[g * 2]     = __builtin_amdgcn_perm(f1.u + 0x8000u, f0.u + 0x8000u, 0x07060302u);
          U[g * 2 + 1] = __builtin_amdgcn_perm(f3.u + 0x8000u, f2.u + 0x8000u, 0x07060302u);
        }
      }

      // O += P V, fragments m = 2*g64 + half; keymap as r3 (no cross-lane P movement)
      __builtin_amdgcn_s_setprio(1);
#pragma unroll
      for (int half = 0; half < 2; half++) {
        const int m = g64 * 2 + half;
        bf16x8 pfrag;
#pragma unroll
        for (int w = 0; w < 4; w++) ((unsigned*)&pfrag)[w] = U[half * 4 + w];
#pragma unroll
        for (int dg = 0; dg < 2; dg++) {
          const ushort* vrow = &Vs[(dg * 32 + ln) * 64];
          bf16x8 vbf;
          *(unsigned long long*)&vbf =
              *(const unsigned long long*)&vrow[(((2 * m) ^ sx) << 3) + 4 * hi];
          *((unsigned long long*)&vbf + 1) =
              *(const unsigned long long*)&vrow[(((2 * m + 1) ^ sx) << 3) + 4 * hi];
          o_acc[dg] = __builtin_amdgcn_mfma_f32_32x32x16_bf16(pfrag, vbf, o_acc[dg], 0, 0, 0);
        }
      }
      __builtin_amdgcn_s_setprio(0);
    }

    __syncthreads();                           // all lanes done reading Ks/Vs
    if (kt + 1 < t1) {
      ATTN_COMMIT();                           // ds_write next tile (waits its vmcnt)
      __syncthreads();                         // LDS ready for next iteration
    }
  }
#undef ATTN_ISSUE
#undef ATTN_COMMIT

  // l: combine hi halves (lane <-> lane^32 hold complementary key sets, same q)
  {
    float lt = l_own + __shfl_xor(l_own, 32);
    if (hi == 0) atomicAdd(&L32[(size_t)bh * 2048 + qg], lt);
  }
  // O partials: lane holds O[q = (r&3)+8*(r>>2)+4hi][dg*32+ln]
#pragma unroll
  for (int r = 0; r < 16; r++) {
    int q = qbw + (r & 3) + ((r >> 2) << 3) + hi * 4;
    size_t orow = ((size_t)(b * 2048) + q) * 1024 + h * 64 + ln;
    atomicAdd(&O32[orow], o_acc[0][r]);
    atomicAdd(&O32[orow + 32], o_acc[1][r]);
  }
}

// ---------------- normalize: O32/l -> bf16 attn_out ----------------
__global__ __launch_bounds__(256) void normalize_kernel(const float* __restrict__ O32,
                                                        const float* __restrict__ L32,
                                                        ushort* __restrict__ Out) {
  const int row = blockIdx.x;            // 0..4095  (b*2048 + t)
  const int tid = threadIdx.x;
  const int col = tid * 4;
  const int b = row >> 11, t = row & 2047, h = col >> 6;
  const float inv = 1.0f / L32[(size_t)(b * 16 + h) * 2048 + t];
  float4 o = ((const float4*)(O32 + (size_t)row * 1024))[tid];
  ushort4 u;
  u.x = f2bf(o.x * inv); u.y = f2bf(o.y * inv);
  u.z = f2bf(o.z * inv); u.w = f2bf(o.w * inv);
  ((ushort4*)(Out + (size_t)row * 1024))[tid] = u;
}

// ---------------- launcher ----------------
extern "C" void kernel_launch(void* const* d_in, const int* in_sizes, int n_in,
                              void* d_out, int out_size, void* d_ws, size_t ws_size,
                              hipStream_t stream) {
  const float* x  = (const float*)d_in[0];
  const float* Wq = (const float*)d_in[1];
  const float* Wk = (const float*)d_in[2];
  const float* Wv = (const float*)d_in[3];
  const float* Wo = (const float*)d_in[4];
  const float* bo = (const float*)d_in[5];
  float* out = (float*)d_out;

  char* ws = (char*)d_ws;
  ushort* xbf  = (ushort*)(ws);                  //  8 MB: x bf16 (dead after gemm_qkv)
  ushort* wcat = (ushort*)(ws + (8ull  << 20));  //  8 MB: Wcat bf16
  ushort* qkv  = (ushort*)(ws + (16ull << 20));  // 24 MB: Q | K | Vt planes
  ushort* Qp   = qkv;
  ushort* Kp   = qkv + (1ull << 22);
  ushort* Vt   = qkv + (2ull << 22);             // V written directly transposed
  float*  L32  = (float*)ws;                     // 256 KB over dead xbf
  float*  O32  = out;                            // d_out as fp32 accumulator scratch
  ushort* attn_out = Qp;                         // Q plane free after attn

  // cast x+weights, zero O32 (12288 blocks = 3M threads)
  cast_all<<<12288, 256, 0, stream>>>(x, Wq, Wk, Wv, Wo, xbf, wcat, (float4*)O32);

  // QKV = x @ Wcat[0:3072]^T; Q pre-scaled by 0.125*log2e; V transposed in epilogue via LDS
  gemm_qkv<<<dim3(24, 32), 256, 0, stream>>>(xbf, wcat, qkv, Vt);

  hipMemsetAsync(L32, 0, (size_t)32 * 2048 * 4, stream);

  attn_kernel<<<dim3(32, 80), 128, 0, stream>>>(Qp, Kp, Vt, O32, L32);

  normalize_kernel<<<4096, 256, 0, stream>>>(O32, L32, attn_out);

  // out = attn_out @ Wo^T + bo   (overwrites O32 scratch, stream-ordered)
  gemm_proj<<<dim3(16, 32), 256, 0, stream>>>(
      attn_out, wcat + (size_t)3072 * 1024, out, bo);
}